// Round 1
// baseline (630.119 us; speedup 1.0000x reference)
//
#include <hip/hip_runtime.h>

#define LOG2E      1.44269504088896340736f
#define TWO_LOG2E  2.88539008177792680472f

__device__ __forceinline__ float frcp(float x)  { return __builtin_amdgcn_rcpf(x); }
__device__ __forceinline__ float fexp2(float x) { return __builtin_amdgcn_exp2f(x); }

// Layout facts (all fp32):
//   images [32, 1024, 64, 16]  -> offset(n,b,s,d) = n*1048576 + b*1024 + s*16 + d
//   t = n*64 + s  (continuous recurrence over 2048 steps)
//   out    [32, 1024, 64, 16]  -> same offset formula, h_j written at d=j
// One wave = one batch chain b. Lane l: j = l>>2 (hidden), g = l&3 (gate),
// weight row r = g*16 + j  (torch gate order i,f,g,o).

__global__ __launch_bounds__(256, 1)
void lstm_fused(const float* __restrict__ images,
                const float* __restrict__ w_ih,
                const float* __restrict__ w_hh,
                const float* __restrict__ b_ih,
                const float* __restrict__ b_hh,
                float* __restrict__ out)
{
    const int lane = threadIdx.x & 63;
    const int wid  = threadIdx.x >> 6;
    const int b    = (blockIdx.x << 2) + wid;   // 0..1023
    const int j    = lane >> 2;
    const int g    = lane & 3;
    const int r    = (g << 4) + j;

    // per-lane weight rows (registers)
    float wih[16], whh[16];
#pragma unroll
    for (int k = 0; k < 4; ++k) {
        float4 a  = *(const float4*)(w_ih + r * 16 + k * 4);
        wih[k*4+0] = a.x; wih[k*4+1] = a.y; wih[k*4+2] = a.z; wih[k*4+3] = a.w;
        float4 c4 = *(const float4*)(w_hh + r * 16 + k * 4);
        whh[k*4+0] = c4.x; whh[k*4+1] = c4.y; whh[k*4+2] = c4.z; whh[k*4+3] = c4.w;
    }
    const float bias = b_ih[r] + b_hh[r];

    // unified activation: act(x) = mm * rcp(1 + exp2(aa*x)) + dd
    //   sigmoid (g=0,1,3): aa = -log2(e), mm = 1,  dd = 0
    //   tanh    (g=2)    : aa = 2log2(e), mm = -2, dd = 1
    const float aa = (g == 2) ? TWO_LOG2E : -LOG2E;
    const float mm = (g == 2) ? -2.0f : 1.0f;
    const float dd = (g == 2) ? 1.0f : 0.0f;

    float hs[16];
#pragma unroll
    for (int k = 0; k < 16; ++k) hs[k] = 0.0f;
    float c = 0.0f;

    const int bbase = b << 10;  // b*1024

    // phase p covers steps t = 4p..4p+3 (always within one n-chunk since 64%4==0)
    // base float offset of phase p:
#define PB(p) ((((p) >> 4) << 20) + bbase + (((((p) << 2)) & 63) << 4))

    // load 4 timesteps of x (64 contiguous floats) for phase p
#define LOADX(buf, p) {                                                        \
        int pc_ = (p); if (pc_ > 511) pc_ = 511;                               \
        const float4* xp_ = (const float4*)(images + PB(pc_));                 \
        _Pragma("unroll")                                                      \
        for (int q = 0; q < 16; ++q) buf[q] = xp_[q]; }

    // xpre[u] = bias + dot(w_ih[r], x_t) for the 4 steps of a phase
#define PROJ(xpre, buf) {                                                      \
        _Pragma("unroll")                                                      \
        for (int u = 0; u < 4; ++u) {                                          \
            float s0 = bias, s1 = 0.f, s2 = 0.f, s3 = 0.f;                     \
            _Pragma("unroll")                                                  \
            for (int kq = 0; kq < 4; ++kq) {                                   \
                float4 xv = buf[u*4 + kq];                                     \
                s0 = fmaf(wih[kq*4+0], xv.x, s0);                              \
                s1 = fmaf(wih[kq*4+1], xv.y, s1);                              \
                s2 = fmaf(wih[kq*4+2], xv.z, s2);                              \
                s3 = fmaf(wih[kq*4+3], xv.w, s3);                              \
            }                                                                  \
            xpre[u] = (s0 + s1) + (s2 + s3);                                   \
        } }

    // one recurrence step; off = flat float offset of (n,b,s,0)
#define STEP(off, xpv) {                                                       \
        float p0 = (xpv), p1 = 0.f, p2 = 0.f, p3 = 0.f;                        \
        _Pragma("unroll")                                                      \
        for (int k = 0; k < 4; ++k) {                                          \
            p0 = fmaf(whh[k],      hs[k],      p0);                            \
            p1 = fmaf(whh[4 + k],  hs[4 + k],  p1);                            \
            p2 = fmaf(whh[8 + k],  hs[8 + k],  p2);                            \
            p3 = fmaf(whh[12 + k], hs[12 + k], p3);                            \
        }                                                                      \
        float pre = (p0 + p1) + (p2 + p3);                                     \
        float act = fmaf(mm, frcp(1.0f + fexp2(aa * pre)), dd);                \
        const int qb_ = lane & ~3;                                             \
        float qi = __shfl(act, qb_ + 0);                                       \
        float qf = __shfl(act, qb_ + 1);                                       \
        float qg = __shfl(act, qb_ + 2);                                       \
        float qo = __shfl(act, qb_ + 3);                                       \
        c = fmaf(qf, c, qi * qg);                                              \
        float tc = fmaf(-2.0f, frcp(1.0f + fexp2(TWO_LOG2E * c)), 1.0f);       \
        float hv = qo * tc;                                                    \
        if (g == 0) out[(off) + j] = hv;                                       \
        _Pragma("unroll")                                                      \
        for (int k = 0; k < 16; ++k)                                           \
            hs[k] = __int_as_float(                                            \
                __builtin_amdgcn_readlane(__float_as_int(hv), k << 2));        \
    }

    float4 bufA[16], bufB[16];
    float  xpre[4];

    // prologue: A=phase0, B=phase1 in flight; consume A into xpre; refill A=phase2
    LOADX(bufA, 0);
    LOADX(bufB, 1);
    PROJ(xpre, bufA);
    LOADX(bufA, 2);

#pragma unroll 1
    for (int p = 0; p < 512; p += 2) {
        {
            const int pb = PB(p);
            STEP(pb,      xpre[0]);
            STEP(pb + 16, xpre[1]);
            STEP(pb + 32, xpre[2]);
            STEP(pb + 48, xpre[3]);
        }
        PROJ(xpre, bufB);          // xpre for phase p+1
        LOADX(bufB, p + 3);        // prefetch ~2 phases ahead
        {
            const int pb = PB(p + 1);
            STEP(pb,      xpre[0]);
            STEP(pb + 16, xpre[1]);
            STEP(pb + 32, xpre[2]);
            STEP(pb + 48, xpre[3]);
        }
        PROJ(xpre, bufA);          // xpre for phase p+2
        LOADX(bufA, p + 4);
    }

#undef STEP
#undef PROJ
#undef LOADX
#undef PB
}

extern "C" void kernel_launch(void* const* d_in, const int* in_sizes, int n_in,
                              void* d_out, int out_size, void* d_ws, size_t ws_size,
                              hipStream_t stream)
{
    const float* images = (const float*)d_in[0];
    const float* w_ih   = (const float*)d_in[1];
    const float* w_hh   = (const float*)d_in[2];
    const float* b_ih   = (const float*)d_in[3];
    const float* b_hh   = (const float*)d_in[4];
    float* outp         = (float*)d_out;

    lstm_fused<<<dim3(256), dim3(256), 0, stream>>>(images, w_ih, w_hh, b_ih, b_hh, outp);
}

// Round 2
// 452.137 us; speedup vs baseline: 1.3936x; 1.3936x over previous
//
#include <hip/hip_runtime.h>

#define LOG2E      1.44269504088896340736f
#define TWO_LOG2E  2.88539008177792680472f

__device__ __forceinline__ float frcp(float x)  { return __builtin_amdgcn_rcpf(x); }
__device__ __forceinline__ float fexp2(float x) { return __builtin_amdgcn_exp2f(x); }

// DPP quad broadcast: every lane of a quad reads the quad's lane K.
template<int PAT>
__device__ __forceinline__ float qperm(float v) {
    return __int_as_float(__builtin_amdgcn_update_dpp(
        0, __float_as_int(v), PAT, 0xF, 0xF, true));
}

// Layout (all fp32):
//   images [32,1024,64,16] -> off(n,b,s,d) = n*1048576 + b*1024 + s*16 + d
//   out    [32,1024,64,16] -> same
// One wave = one chain b. Lane l: j = l>>2 (hidden unit), g = l&3 (gate),
// weight row r = g*16 + j (torch order i,f,g,o).
// Pre-scaling: rows of w_ih/w_hh and bias are multiplied by aa (the exponent
// coefficient of that gate's activation), so the dot product directly yields
// the exp2 argument. g-gate (tanh) output is additionally scaled by K=2log2e
// so that c' = K*c is tracked and tanh(c) = 1 - 2*rcp(1+exp2(c')).

__global__ __launch_bounds__(256, 1)
void lstm_fused(const float* __restrict__ images,
                const float* __restrict__ w_ih,
                const float* __restrict__ w_hh,
                const float* __restrict__ b_ih,
                const float* __restrict__ b_hh,
                float* __restrict__ out)
{
    const int lane = threadIdx.x & 63;
    const int wid  = threadIdx.x >> 6;
    const int b    = (blockIdx.x << 2) + wid;   // 0..1023
    const int j    = lane >> 2;
    const int g    = lane & 3;
    const int r    = (g << 4) + j;

    // activation constants: sigmoid (g=0,1,3): aa=-log2e, mm=1,   dd=0
    //                       tanh*K  (g=2)    : aa=2log2e, mm=-2K, dd=K
    const float aa = (g == 2) ? TWO_LOG2E : -LOG2E;
    const float mm = (g == 2) ? -2.0f * TWO_LOG2E : 1.0f;
    const float dd = (g == 2) ? TWO_LOG2E : 0.0f;

    // per-lane pre-scaled weight rows
    float wih[16], whh[16];
#pragma unroll
    for (int k = 0; k < 4; ++k) {
        float4 a  = *(const float4*)(w_ih + r * 16 + k * 4);
        wih[k*4+0] = aa*a.x; wih[k*4+1] = aa*a.y; wih[k*4+2] = aa*a.z; wih[k*4+3] = aa*a.w;
        float4 c4 = *(const float4*)(w_hh + r * 16 + k * 4);
        whh[k*4+0] = aa*c4.x; whh[k*4+1] = aa*c4.y; whh[k*4+2] = aa*c4.z; whh[k*4+3] = aa*c4.w;
    }
    const float bias = aa * (b_ih[r] + b_hh[r]);

    float hs[16];
#pragma unroll
    for (int k = 0; k < 16; ++k) hs[k] = 0.0f;
    float c = 0.0f;      // tracks K * c_true
    float sv = 0.0f;     // per-phase store value

    const int bbase = b << 10;  // b*1024

    // phase p covers steps t = 4p..4p+3; base float offset:
#define PB(p) ((((p) >> 4) << 20) + bbase + (((((p) << 2)) & 63) << 4))

#define LOADX(buf, p) {                                                        \
        int pc_ = (p); if (pc_ > 511) pc_ = 511;                               \
        const float4* xp_ = (const float4*)(images + PB(pc_));                 \
        _Pragma("unroll")                                                      \
        for (int q = 0; q < 16; ++q) buf[q] = xp_[q]; }

    // xpre[u] = bias_scaled + dot(wih_scaled, x_t) for the 4 steps of a phase
#define PROJ(xpre, buf) {                                                      \
        _Pragma("unroll")                                                      \
        for (int u = 0; u < 4; ++u) {                                          \
            float s0 = bias, s1 = 0.f, s2 = 0.f, s3 = 0.f;                     \
            _Pragma("unroll")                                                  \
            for (int kq = 0; kq < 4; ++kq) {                                   \
                float4 xv = buf[u*4 + kq];                                     \
                s0 = fmaf(wih[kq*4+0], xv.x, s0);                              \
                s1 = fmaf(wih[kq*4+1], xv.y, s1);                              \
                s2 = fmaf(wih[kq*4+2], xv.z, s2);                              \
                s3 = fmaf(wih[kq*4+3], xv.w, s3);                              \
            }                                                                  \
            xpre[u] = (s0 + s1) + (s2 + s3);                                   \
        } }

    // one recurrence step (u = step-in-phase literal)
#define STEP(u, xpv) {                                                         \
        float p0 = (xpv), p1 = 0.f, p2 = 0.f, p3 = 0.f;                        \
        _Pragma("unroll")                                                      \
        for (int k = 0; k < 4; ++k) {                                          \
            p0 = fmaf(whh[k],      hs[k],      p0);                            \
            p1 = fmaf(whh[4 + k],  hs[4 + k],  p1);                            \
            p2 = fmaf(whh[8 + k],  hs[8 + k],  p2);                            \
            p3 = fmaf(whh[12 + k], hs[12 + k], p3);                            \
        }                                                                      \
        float arg = (p0 + p1) + (p2 + p3);                                     \
        float act = fmaf(mm, frcp(1.0f + fexp2(arg)), dd);                     \
        float qi = qperm<0x00>(act);                                           \
        float qf = qperm<0x55>(act);                                           \
        float qg = qperm<0xAA>(act);                                           \
        float qo = qperm<0xFF>(act);                                           \
        c = fmaf(qf, c, qi * qg);                                              \
        float tc = fmaf(-2.0f, frcp(1.0f + fexp2(c)), 1.0f);                   \
        float hv = qo * tc;                                                    \
        sv = (g == (u)) ? hv : sv;                                             \
        _Pragma("unroll")                                                      \
        for (int k = 0; k < 16; ++k)                                           \
            hs[k] = __int_as_float(                                            \
                __builtin_amdgcn_readlane(__float_as_int(hv), k << 2));        \
    }

    // coalesced per-phase store: lane 4j+g stores (step g, unit j)
#define STORE(pb) out[(pb) + ((lane & 3) << 4) + (lane >> 2)] = sv;

    float4 bufA[16], bufB[16];
    float  xpre[4];

    LOADX(bufA, 0);
    LOADX(bufB, 1);
    PROJ(xpre, bufA);
    LOADX(bufA, 2);

#pragma unroll 1
    for (int p = 0; p < 512; p += 2) {
        {
            const int pb = PB(p);
            STEP(0, xpre[0]);
            STEP(1, xpre[1]);
            STEP(2, xpre[2]);
            STEP(3, xpre[3]);
            STORE(pb);
        }
        PROJ(xpre, bufB);          // xpre for phase p+1
        LOADX(bufB, p + 3);        // prefetch ~2 phases ahead
        {
            const int pb = PB(p + 1);
            STEP(0, xpre[0]);
            STEP(1, xpre[1]);
            STEP(2, xpre[2]);
            STEP(3, xpre[3]);
            STORE(pb);
        }
        PROJ(xpre, bufA);          // xpre for phase p+2
        LOADX(bufA, p + 4);
    }

#undef STEP
#undef STORE
#undef PROJ
#undef LOADX
#undef PB
}

extern "C" void kernel_launch(void* const* d_in, const int* in_sizes, int n_in,
                              void* d_out, int out_size, void* d_ws, size_t ws_size,
                              hipStream_t stream)
{
    const float* images = (const float*)d_in[0];
    const float* w_ih   = (const float*)d_in[1];
    const float* w_hh   = (const float*)d_in[2];
    const float* b_ih   = (const float*)d_in[3];
    const float* b_hh   = (const float*)d_in[4];
    float* outp         = (float*)d_out;

    lstm_fused<<<dim3(256), dim3(256), 0, stream>>>(images, w_ih, w_hh, b_ih, b_hh, outp);
}

// Round 3
// 383.149 us; speedup vs baseline: 1.6446x; 1.1801x over previous
//
#include <hip/hip_runtime.h>

#define LOG2E      1.44269504088896340736f
#define TWO_LOG2E  2.88539008177792680472f

__device__ __forceinline__ float frcp(float x)  { return __builtin_amdgcn_rcpf(x); }
__device__ __forceinline__ float fexp2(float x) { return __builtin_amdgcn_exp2f(x); }

// DPP quad broadcast: every lane of a quad reads the quad's lane K.
template<int PAT>
__device__ __forceinline__ float qperm(float v) {
    return __int_as_float(__builtin_amdgcn_update_dpp(
        0, __float_as_int(v), PAT, 0xF, 0xF, true));
}

// async global->LDS, 16B per lane. LDS dest = wave-uniform base + lane*16.
__device__ __forceinline__ void gload_lds16(const float* g, float* l) {
    auto gp = (const __attribute__((address_space(1))) float*)g;
    auto lp = (__attribute__((address_space(3))) float*)l;
    __builtin_amdgcn_global_load_lds(gp, lp, 16, 0, 0);
}

// Layout (all fp32):
//   images [32,1024,64,16] -> off(n,b,s,d) = n*1048576 + b*1024 + s*16 + d
//   out    [32,1024,64,16] -> same
// One wave = one chain b. Lane l: j = l>>2 (hidden unit), g = l&3 (gate),
// weight row r = g*16 + j (torch order i,f,g,o).
// Weights/bias pre-scaled by the activation's exp2 coefficient; the tanh
// gate additionally folds K=2log2e so c' = K*c is tracked.
// x staging: per wave, chunk n's [64,16] slice (4 KB) lives in LDS,
// double-buffered, filled by 4 global_load_lds issued ~16 phases early.

__global__ __launch_bounds__(256, 1)
void lstm_fused(const float* __restrict__ images,
                const float* __restrict__ w_ih,
                const float* __restrict__ w_hh,
                const float* __restrict__ b_ih,
                const float* __restrict__ b_hh,
                float* __restrict__ out)
{
    __shared__ float4 xlds[4][2][256];   // [wave][buf][1 KB as float4] = 32 KB

    const int lane = threadIdx.x & 63;
    const int wid  = threadIdx.x >> 6;
    const int b    = (blockIdx.x << 2) + wid;   // 0..1023
    const int j    = lane >> 2;
    const int g    = lane & 3;
    const int r    = (g << 4) + j;

    // sigmoid (g=0,1,3): aa=-log2e, mm=1,   dd=0
    // tanh*K  (g=2)    : aa=2log2e, mm=-2K, dd=K
    const float aa = (g == 2) ? TWO_LOG2E : -LOG2E;
    const float mm = (g == 2) ? -2.0f * TWO_LOG2E : 1.0f;
    const float dd = (g == 2) ? TWO_LOG2E : 0.0f;

    float wih[16], whh[16];
#pragma unroll
    for (int k = 0; k < 4; ++k) {
        float4 a  = *(const float4*)(w_ih + r * 16 + k * 4);
        wih[k*4+0] = aa*a.x; wih[k*4+1] = aa*a.y; wih[k*4+2] = aa*a.z; wih[k*4+3] = aa*a.w;
        float4 c4 = *(const float4*)(w_hh + r * 16 + k * 4);
        whh[k*4+0] = aa*c4.x; whh[k*4+1] = aa*c4.y; whh[k*4+2] = aa*c4.z; whh[k*4+3] = aa*c4.w;
    }
    const float bias = aa * (b_ih[r] + b_hh[r]);

    float hs[16];
#pragma unroll
    for (int k = 0; k < 16; ++k) hs[k] = 0.0f;
    float c = 0.0f;      // tracks K * c_true
    float sv = 0.0f;     // per-phase store value

    const int bbase = b << 10;  // b*1024

    // phase P covers steps t = 4P..4P+3; output/input base float offset:
#define PB(p) ((((p) >> 4) << 20) + bbase + (((((p) << 2)) & 63) << 4))

    // stage chunk n (4 KB) into LDS buf n&1 via 4 async 16B/lane loads
#define GLOAD_CHUNK(n) {                                                       \
        const float* gp_ = images + ((n) << 20) + bbase + (lane << 2);         \
        float4* lb_ = &xlds[wid][(n) & 1][0];                                  \
        gload_lds16(gp_ + 0,   (float*)(lb_ + 0));                             \
        gload_lds16(gp_ + 256, (float*)(lb_ + 64));                            \
        gload_lds16(gp_ + 512, (float*)(lb_ + 128));                           \
        gload_lds16(gp_ + 768, (float*)(lb_ + 192)); }

    // read phase Q's 4 timesteps (64 floats) from LDS (uniform addr broadcast)
#define DSREAD(xv, Qraw) {                                                     \
        int Q_ = (Qraw); if (Q_ > 511) Q_ = 511;                               \
        const float4* sp_ = &xlds[wid][(Q_ >> 4) & 1][(Q_ & 15) << 4];         \
        _Pragma("unroll")                                                      \
        for (int q = 0; q < 16; ++q) xv[q] = sp_[q]; }

    // xpre[u] = scaled bias + dot(scaled w_ih, x_t) for the phase's 4 steps
#define PROJ(xpre, buf) {                                                      \
        _Pragma("unroll")                                                      \
        for (int u = 0; u < 4; ++u) {                                          \
            float s0 = bias, s1 = 0.f, s2 = 0.f, s3 = 0.f;                     \
            _Pragma("unroll")                                                  \
            for (int kq = 0; kq < 4; ++kq) {                                   \
                float4 xv = buf[u*4 + kq];                                     \
                s0 = fmaf(wih[kq*4+0], xv.x, s0);                              \
                s1 = fmaf(wih[kq*4+1], xv.y, s1);                              \
                s2 = fmaf(wih[kq*4+2], xv.z, s2);                              \
                s3 = fmaf(wih[kq*4+3], xv.w, s3);                              \
            }                                                                  \
            xpre[u] = (s0 + s1) + (s2 + s3);                                   \
        } }

    // one recurrence step (u = step-in-phase literal)
#define STEP(u, xpv) {                                                         \
        float p0 = (xpv), p1 = 0.f, p2 = 0.f, p3 = 0.f;                        \
        _Pragma("unroll")                                                      \
        for (int k = 0; k < 4; ++k) {                                          \
            p0 = fmaf(whh[k],      hs[k],      p0);                            \
            p1 = fmaf(whh[4 + k],  hs[4 + k],  p1);                            \
            p2 = fmaf(whh[8 + k],  hs[8 + k],  p2);                            \
            p3 = fmaf(whh[12 + k], hs[12 + k], p3);                            \
        }                                                                      \
        float arg = (p0 + p1) + (p2 + p3);                                     \
        float act = fmaf(mm, frcp(1.0f + fexp2(arg)), dd);                     \
        float qi = qperm<0x00>(act);                                           \
        float qf = qperm<0x55>(act);                                           \
        float qg = qperm<0xAA>(act);                                           \
        float qo = qperm<0xFF>(act);                                           \
        c = fmaf(qf, c, qi * qg);                                              \
        float tc = fmaf(-2.0f, frcp(1.0f + fexp2(c)), 1.0f);                   \
        float hv = qo * tc;                                                    \
        sv = (g == (u)) ? hv : sv;                                             \
        _Pragma("unroll")                                                      \
        for (int k = 0; k < 16; ++k)                                           \
            hs[k] = __int_as_float(                                            \
                __builtin_amdgcn_readlane(__float_as_int(hv), k << 2));        \
    }

    // coalesced per-phase store: lane 4j+g stores (step g, unit j)
#define STORE(pb) out[(pb) + ((lane & 3) << 4) + (lane >> 2)] = sv;

    float4 xvA[16], xvB[16];
    float  xpre[4];

    // prologue: stage chunks 0 and 1; prime the phase pipeline
    GLOAD_CHUNK(0);
    GLOAD_CHUNK(1);
    DSREAD(xvA, 0);          // compiler inserts vmcnt wait for chunk 0 here
    PROJ(xpre, xvA);
    DSREAD(xvB, 1);

#pragma unroll 1
    for (int P = 0; P < 512; P += 2) {
        {
            const int pb = PB(P);
            STEP(0, xpre[0]);
            STEP(1, xpre[1]);
            STEP(2, xpre[2]);
            STEP(3, xpre[3]);
            STORE(pb);
        }
        PROJ(xpre, xvB);               // project phase P+1
        DSREAD(xvA, P + 2);            // pull phase P+2 from LDS
        if ((P & 15) == 14 && P < 480) // once per chunk: stage chunk+2
            GLOAD_CHUNK((P >> 4) + 2);
        {
            const int pb = PB(P + 1);
            STEP(0, xpre[0]);
            STEP(1, xpre[1]);
            STEP(2, xpre[2]);
            STEP(3, xpre[3]);
            STORE(pb);
        }
        PROJ(xpre, xvA);               // project phase P+2
        DSREAD(xvB, P + 3);            // pull phase P+3 from LDS
    }

#undef STEP
#undef STORE
#undef PROJ
#undef DSREAD
#undef GLOAD_CHUNK
#undef PB
}

extern "C" void kernel_launch(void* const* d_in, const int* in_sizes, int n_in,
                              void* d_out, int out_size, void* d_ws, size_t ws_size,
                              hipStream_t stream)
{
    const float* images = (const float*)d_in[0];
    const float* w_ih   = (const float*)d_in[1];
    const float* w_hh   = (const float*)d_in[2];
    const float* b_ih   = (const float*)d_in[3];
    const float* b_hh   = (const float*)d_in[4];
    float* outp         = (float*)d_out;

    lstm_fused<<<dim3(256), dim3(256), 0, stream>>>(images, w_ih, w_hh, b_ih, b_hh, outp);
}

// Round 4
// 324.142 us; speedup vs baseline: 1.9440x; 1.1820x over previous
//
#include <hip/hip_runtime.h>

#define LOG2E      1.44269504088896340736f
#define TWO_LOG2E  2.88539008177792680472f

typedef float f2 __attribute__((ext_vector_type(2)));

__device__ __forceinline__ float frcp(float x)  { return __builtin_amdgcn_rcpf(x); }
__device__ __forceinline__ float fexp2(float x) { return __builtin_amdgcn_exp2f(x); }

__device__ __forceinline__ f2 pk_mul(f2 a, f2 b) {
    f2 d; asm("v_pk_mul_f32 %0, %1, %2" : "=v"(d) : "v"(a), "v"(b)); return d;
}
__device__ __forceinline__ f2 pk_fma(f2 a, f2 b, f2 c) {
    f2 d; asm("v_pk_fma_f32 %0, %1, %2, %3" : "=v"(d) : "v"(a), "v"(b), "v"(c)); return d;
}
__device__ __forceinline__ f2 pk_add(f2 a, f2 b) {
    f2 d; asm("v_pk_add_f32 %0, %1, %2" : "=v"(d) : "v"(a), "v"(b)); return d;
}

// async global->LDS, 16B per lane. LDS dest = wave-uniform base + lane*16.
__device__ __forceinline__ void gload_lds16(const float* g, float* l) {
    auto gp = (const __attribute__((address_space(1))) float*)g;
    auto lp = (__attribute__((address_space(3))) float*)l;
    __builtin_amdgcn_global_load_lds(gp, lp, 16, 0, 0);
}

// Layout (all fp32):
//   images [32,1024,64,16] -> off(n,b,s,d) = n*1048576 + b*1024 + s*16 + d
//   out    [32,1024,64,16] -> same
// One wave = one chain b. ROW-MAJOR lane map: row a = lane>>4 (a gate, mapping
// probed at runtime), pos j = lane&15 (hidden unit). Weight row = gate*16+j.
// Every 16-lane row computes all 16 h values at positions 0..15, so the
// recurrent dot is 16 DPP row_ror fmacs on hv (no broadcast, no SGPR hazard).
// Gates i,f,g,o (same pos, 4 rows) gathered via permlane16/32_swap.
// Weights/bias pre-scaled by the activation's exp2 coefficient; tanh gate
// folds K=2log2e so c' = K*c is tracked.

__global__ __launch_bounds__(256, 1)
void lstm_fused(const float* __restrict__ images,
                const float* __restrict__ w_ih,
                const float* __restrict__ w_hh,
                const float* __restrict__ b_ih,
                const float* __restrict__ b_hh,
                float* __restrict__ out)
{
    __shared__ float4 xlds[4][2][256];   // [wave][buf][1 KB as float4] = 32 KB

    const int lane = threadIdx.x & 63;
    const int wid  = threadIdx.x >> 6;
    const int b    = (blockIdx.x << 2) + wid;   // 0..1023
    const int a    = lane >> 4;                 // row 0..3
    const int j    = lane & 15;                 // unit 0..15

    // ---- runtime convention probes (init-only) ----
    // row_ror direction: after row_ror:1, which source pos do I see?
    int rr1 = __builtin_amdgcn_update_dpp(0, j, 0x121, 0xF, 0xF, true);
    const int d_ror = (rr1 - j) & 15;           // src pos of ror:t = (j + d_ror*t)&15

    // permlane16_swap: first operand ends with even-or-odd row of its pair?
    int e16;
    { int pa = a, pb = a;
      asm volatile("s_nop 1\n\t"
                   "v_permlane16_swap_b32 %0, %1" : "+v"(pa), "+v"(pb));
      e16 = pa & 1; }                            // 0: first out = even row
    // permlane32_swap: first operand ends with lower-or-upper half?
    int e32;
    { int pc = a, pd = a;
      asm volatile("s_nop 1\n\t"
                   "v_permlane32_swap_b32 %0, %1" : "+v"(pc), "+v"(pd));
      e32 = (pc < 2) ? 0 : 1; }                  // 0: first out = lower half

    // Choose row->gate mapping so that after (p16; p32,p32) the outputs are
    // exactly (qf, qg, qi, qo):  row[(e32<<1)|e16]=f, row[((1^e32)<<1)|e16]=g,
    // row[(e32<<1)|(1^e16)]=i, row[((1^e32)<<1)|(1^e16)]=o.
    const int m1 = ((a >> 1) == e32);
    const int m0 = ((a & 1) == e16);
    const int gate = m0 ? (m1 ? 1 : 2) : (m1 ? 0 : 3);  // torch: i=0,f=1,g=2,o=3
    const int r = gate * 16 + j;

    // sigmoid gates: aa=-log2e, mm=1, dd=0 ; tanh*K gate: aa=2log2e, mm=-2K, dd=K
    const float aa = (gate == 2) ? TWO_LOG2E : -LOG2E;
    const float mm = (gate == 2) ? -2.0f * TWO_LOG2E : 1.0f;
    const float dd = (gate == 2) ? TWO_LOG2E : 0.0f;

    // recurrent weights, slot t matches row_ror:t source pos
    float whh[16];
#pragma unroll
    for (int t = 0; t < 16; ++t)
        whh[t] = aa * w_hh[r * 16 + ((j + d_ror * t) & 15)];
    // input weights as packed pairs
    f2 wihp[8];
#pragma unroll
    for (int m = 0; m < 8; ++m) {
        f2 w; w.x = aa * w_ih[r * 16 + 2 * m]; w.y = aa * w_ih[r * 16 + 2 * m + 1];
        wihp[m] = w;
    }
    const float bias = aa * (b_ih[r] + b_hh[r]);

    float hv = 0.0f;   // h[j], replicated across rows
    float c  = 0.0f;   // K * c_true
    float sv = 0.0f;   // per-phase store value (row a holds step a)

    const int bbase = b << 10;  // b*1024

    // phase P covers steps t = 4P..4P+3; base float offset:
#define PB(p) ((((p) >> 4) << 20) + bbase + (((((p) << 2)) & 63) << 4))

    // stage chunk n (4 KB) into LDS buf n&1 via 4 async 16B/lane loads
#define GLOAD_CHUNK(n) {                                                       \
        const float* gp_ = images + ((n) << 20) + bbase + (lane << 2);         \
        float4* lb_ = &xlds[wid][(n) & 1][0];                                  \
        gload_lds16(gp_ + 0,   (float*)(lb_ + 0));                             \
        gload_lds16(gp_ + 256, (float*)(lb_ + 64));                            \
        gload_lds16(gp_ + 512, (float*)(lb_ + 128));                           \
        gload_lds16(gp_ + 768, (float*)(lb_ + 192)); }

    // read phase Q's 4 timesteps (64 floats) from LDS as f2 pairs
#define DSREAD(xv2, Qraw) {                                                    \
        int Q_ = (Qraw); if (Q_ > 511) Q_ = 511;                               \
        const float4* sp_ = &xlds[wid][(Q_ >> 4) & 1][(Q_ & 15) << 4];         \
        _Pragma("unroll")                                                      \
        for (int q = 0; q < 16; ++q) {                                         \
            float4 t_ = sp_[q];                                                \
            f2 lo_, hi_; lo_.x = t_.x; lo_.y = t_.y; hi_.x = t_.z; hi_.y = t_.w;\
            xv2[2*q] = lo_; xv2[2*q+1] = hi_;                                  \
        } }

    // xpre[u] = scaled bias + dot(scaled w_ih, x_t), packed-fp32
#define PROJ(xpre, x2) {                                                       \
        _Pragma("unroll")                                                      \
        for (int u = 0; u < 4; ++u) {                                          \
            f2 A_ = pk_mul(wihp[0], x2[8*u+0]);                                \
            f2 B_ = pk_mul(wihp[1], x2[8*u+1]);                                \
            A_ = pk_fma(wihp[2], x2[8*u+2], A_);                               \
            B_ = pk_fma(wihp[3], x2[8*u+3], B_);                               \
            A_ = pk_fma(wihp[4], x2[8*u+4], A_);                               \
            B_ = pk_fma(wihp[5], x2[8*u+5], B_);                               \
            A_ = pk_fma(wihp[6], x2[8*u+6], A_);                               \
            B_ = pk_fma(wihp[7], x2[8*u+7], B_);                               \
            A_ = pk_add(A_, B_);                                               \
            xpre[u] = (bias + A_.x) + A_.y;                                    \
        } }

    // one recurrence step (u = step-in-phase literal)
#define STEP(u, xpv) {                                                         \
        float p0 = (xpv), p1, p2, p3;                                          \
        asm volatile(                                                          \
          "s_nop 1\n\t"                                                        \
          "v_fmac_f32 %[q0], %[h], %[w0]\n\t"                                  \
          "v_mul_f32 %[q1], %[h], %[w1] row_ror:1 row_mask:0xf bank_mask:0xf\n\t" \
          "v_mul_f32 %[q2], %[h], %[w2] row_ror:2 row_mask:0xf bank_mask:0xf\n\t" \
          "v_mul_f32 %[q3], %[h], %[w3] row_ror:3 row_mask:0xf bank_mask:0xf\n\t" \
          "v_fmac_f32 %[q0], %[h], %[w4] row_ror:4 row_mask:0xf bank_mask:0xf\n\t" \
          "v_fmac_f32 %[q1], %[h], %[w5] row_ror:5 row_mask:0xf bank_mask:0xf\n\t" \
          "v_fmac_f32 %[q2], %[h], %[w6] row_ror:6 row_mask:0xf bank_mask:0xf\n\t" \
          "v_fmac_f32 %[q3], %[h], %[w7] row_ror:7 row_mask:0xf bank_mask:0xf\n\t" \
          "v_fmac_f32 %[q0], %[h], %[w8] row_ror:8 row_mask:0xf bank_mask:0xf\n\t" \
          "v_fmac_f32 %[q1], %[h], %[w9] row_ror:9 row_mask:0xf bank_mask:0xf\n\t" \
          "v_fmac_f32 %[q2], %[h], %[w10] row_ror:10 row_mask:0xf bank_mask:0xf\n\t" \
          "v_fmac_f32 %[q3], %[h], %[w11] row_ror:11 row_mask:0xf bank_mask:0xf\n\t" \
          "v_fmac_f32 %[q0], %[h], %[w12] row_ror:12 row_mask:0xf bank_mask:0xf\n\t" \
          "v_fmac_f32 %[q1], %[h], %[w13] row_ror:13 row_mask:0xf bank_mask:0xf\n\t" \
          "v_fmac_f32 %[q2], %[h], %[w14] row_ror:14 row_mask:0xf bank_mask:0xf\n\t" \
          "v_fmac_f32 %[q3], %[h], %[w15] row_ror:15 row_mask:0xf bank_mask:0xf"   \
          : [q0]"+v"(p0), [q1]"=&v"(p1), [q2]"=&v"(p2), [q3]"=&v"(p3)          \
          : [h]"v"(hv),                                                        \
            [w0]"v"(whh[0]),  [w1]"v"(whh[1]),  [w2]"v"(whh[2]),  [w3]"v"(whh[3]), \
            [w4]"v"(whh[4]),  [w5]"v"(whh[5]),  [w6]"v"(whh[6]),  [w7]"v"(whh[7]), \
            [w8]"v"(whh[8]),  [w9]"v"(whh[9]),  [w10]"v"(whh[10]),[w11]"v"(whh[11]),\
            [w12]"v"(whh[12]),[w13]"v"(whh[13]),[w14]"v"(whh[14]),[w15]"v"(whh[15]));\
        float arg = (p0 + p1) + (p2 + p3);                                     \
        float act = fmaf(mm, frcp(1.0f + fexp2(arg)), dd);                     \
        float qf, qg, qi, qo;                                                  \
        asm volatile(                                                          \
          "v_mov_b32 %[A], %[x]\n\t"                                           \
          "v_mov_b32 %[B], %[x]\n\t"                                           \
          "s_nop 1\n\t"                                                        \
          "v_permlane16_swap_b32 %[A], %[B]\n\t"                               \
          "v_mov_b32 %[C], %[A]\n\t"                                           \
          "v_mov_b32 %[D], %[B]\n\t"                                           \
          "v_permlane32_swap_b32 %[A], %[C]\n\t"                               \
          "v_permlane32_swap_b32 %[B], %[D]"                                   \
          : [A]"=&v"(qf), [B]"=&v"(qi), [C]"=&v"(qg), [D]"=&v"(qo)             \
          : [x]"v"(act));                                                      \
        c = fmaf(c, qf, qi * qg);                                              \
        float tc = fmaf(-2.0f, frcp(1.0f + fexp2(c)), 1.0f);                   \
        hv = qo * tc;                                                          \
        sv = (a == (u)) ? hv : sv;                                             \
    }

    // coalesced per-phase store: lane l = 16*step + unit
#define STORE(pb) out[(pb) + lane] = sv;

    f2    xvA[32], xvB[32];
    float xpre[4];

    // prologue: stage chunks 0 and 1; prime the phase pipeline
    GLOAD_CHUNK(0);
    GLOAD_CHUNK(1);
    DSREAD(xvA, 0);
    PROJ(xpre, xvA);
    DSREAD(xvB, 1);

#pragma unroll 1
    for (int P = 0; P < 512; P += 2) {
        {
            const int pb = PB(P);
            STEP(0, xpre[0]);
            STEP(1, xpre[1]);
            STEP(2, xpre[2]);
            STEP(3, xpre[3]);
            STORE(pb);
        }
        PROJ(xpre, xvB);               // project phase P+1
        DSREAD(xvA, P + 2);            // pull phase P+2 from LDS
        if ((P & 15) == 14 && P < 480) // once per chunk: stage chunk+2
            GLOAD_CHUNK((P >> 4) + 2);
        {
            const int pb = PB(P + 1);
            STEP(0, xpre[0]);
            STEP(1, xpre[1]);
            STEP(2, xpre[2]);
            STEP(3, xpre[3]);
            STORE(pb);
        }
        PROJ(xpre, xvA);               // project phase P+2
        DSREAD(xvB, P + 3);            // pull phase P+3 from LDS
    }

#undef STEP
#undef STORE
#undef PROJ
#undef DSREAD
#undef GLOAD_CHUNK
#undef PB
}

extern "C" void kernel_launch(void* const* d_in, const int* in_sizes, int n_in,
                              void* d_out, int out_size, void* d_ws, size_t ws_size,
                              hipStream_t stream)
{
    const float* images = (const float*)d_in[0];
    const float* w_ih   = (const float*)d_in[1];
    const float* w_hh   = (const float*)d_in[2];
    const float* b_ih   = (const float*)d_in[3];
    const float* b_hh   = (const float*)d_in[4];
    float* outp         = (float*)d_out;

    lstm_fused<<<dim3(256), dim3(256), 0, stream>>>(images, w_ih, w_hh, b_ih, b_hh, outp);
}

// Round 5
// 292.605 us; speedup vs baseline: 2.1535x; 1.1078x over previous
//
#include <hip/hip_runtime.h>

#define LOG2E      1.44269504088896340736f
#define TWO_LOG2E  2.88539008177792680472f

typedef float f2 __attribute__((ext_vector_type(2)));

__device__ __forceinline__ float frcp(float x)  { return __builtin_amdgcn_rcpf(x); }
__device__ __forceinline__ float fexp2(float x) { return __builtin_amdgcn_exp2f(x); }

__device__ __forceinline__ f2 pk_mul(f2 a, f2 b) {
    f2 d; asm("v_pk_mul_f32 %0, %1, %2" : "=v"(d) : "v"(a), "v"(b)); return d;
}
__device__ __forceinline__ f2 pk_fma(f2 a, f2 b, f2 c) {
    f2 d; asm("v_pk_fma_f32 %0, %1, %2, %3" : "=v"(d) : "v"(a), "v"(b), "v"(c)); return d;
}
__device__ __forceinline__ f2 pk_add(f2 a, f2 b) {
    f2 d; asm("v_pk_add_f32 %0, %1, %2" : "=v"(d) : "v"(a), "v"(b)); return d;
}
__device__ __forceinline__ f2 f2lo(float4 v) { f2 r; r.x = v.x; r.y = v.y; return r; }
__device__ __forceinline__ f2 f2hi(float4 v) { f2 r; r.x = v.z; r.y = v.w; return r; }

// async global->LDS, 16B per lane. LDS dest = wave-uniform base + lane*16.
__device__ __forceinline__ void gload_lds16(const float* g, float* l) {
    auto gp = (const __attribute__((address_space(1))) float*)g;
    auto lp = (__attribute__((address_space(3))) float*)l;
    __builtin_amdgcn_global_load_lds(gp, lp, 16, 0, 0);
}

// Layout (all fp32):
//   images [32,1024,64,16] -> off(n,b,s,d) = n*1048576 + b*1024 + s*16 + d
//   out    [32,1024,64,16] -> same
// One wave = one chain b. ROW-MAJOR lane map: row a = lane>>4 (a gate, mapping
// probed at runtime), pos j = lane&15 (hidden unit). Weight row = gate*16+j.
// Recurrent dot = 16 DPP row_ror fmacs on hv. Gates gathered via
// permlane16/32_swap. Weights/bias pre-scaled by each activation's exp2
// coefficient; tanh gate folds K=2log2e so c' = K*c is tracked.
// x pipeline: chunk staged to LDS by global_load_lds 2 chunks early;
// per-phase x pulled to VGPRs by PINNED volatile asm ds_read_b128 issued
// ~4 steps before the lgkmcnt(0)+sched_barrier that guards its PROJ.

__global__ __launch_bounds__(256, 1)
void lstm_fused(const float* __restrict__ images,
                const float* __restrict__ w_ih,
                const float* __restrict__ w_hh,
                const float* __restrict__ b_ih,
                const float* __restrict__ b_hh,
                float* __restrict__ out)
{
    __shared__ float4 xlds[4][2][256];   // [wave][buf][1 KB as float4] = 32 KB

    const int lane = threadIdx.x & 63;
    const int wid  = threadIdx.x >> 6;
    const int b    = (blockIdx.x << 2) + wid;   // 0..1023
    const int a    = lane >> 4;                 // row 0..3
    const int j    = lane & 15;                 // unit 0..15

    // ---- runtime convention probes (init-only; verified passing in R4) ----
    int rr1 = __builtin_amdgcn_update_dpp(0, j, 0x121, 0xF, 0xF, true);
    const int d_ror = (rr1 - j) & 15;           // src pos of ror:t = (j + d_ror*t)&15

    int e16;
    { int pa = a, pb = a;
      asm volatile("s_nop 1\n\t"
                   "v_permlane16_swap_b32 %0, %1" : "+v"(pa), "+v"(pb));
      e16 = pa & 1; }
    int e32;
    { int pc = a, pd = a;
      asm volatile("s_nop 1\n\t"
                   "v_permlane32_swap_b32 %0, %1" : "+v"(pc), "+v"(pd));
      e32 = (pc < 2) ? 0 : 1; }

    const int m1 = ((a >> 1) == e32);
    const int m0 = ((a & 1) == e16);
    const int gate = m0 ? (m1 ? 1 : 2) : (m1 ? 0 : 3);  // torch: i=0,f=1,g=2,o=3
    const int r = gate * 16 + j;

    const float aa = (gate == 2) ? TWO_LOG2E : -LOG2E;
    const float mm = (gate == 2) ? -2.0f * TWO_LOG2E : 1.0f;
    const float dd = (gate == 2) ? TWO_LOG2E : 0.0f;

    float whh[16];
#pragma unroll
    for (int t = 0; t < 16; ++t)
        whh[t] = aa * w_hh[r * 16 + ((j + d_ror * t) & 15)];
    f2 wihp[8];
#pragma unroll
    for (int m = 0; m < 8; ++m) {
        f2 w; w.x = aa * w_ih[r * 16 + 2 * m]; w.y = aa * w_ih[r * 16 + 2 * m + 1];
        wihp[m] = w;
    }
    const float bias = aa * (b_ih[r] + b_hh[r]);

    // hoisted store-select masks (one v_cmp each, off the serial path)
    const bool su0 = (a == 0), su1 = (a == 1), su2 = (a == 2), su3 = (a == 3);

    float hv = 0.0f;   // h[j], replicated across rows
    float c  = 0.0f;   // K * c_true
    float sv = 0.0f;   // per-phase store value (row a holds step a)

    const int bbase = b << 10;  // b*1024

#define PB(p) ((((p) >> 4) << 20) + bbase + (((((p) << 2)) & 63) << 4))

#define GLOAD_CHUNK(n) {                                                       \
        const float* gp_ = images + ((n) << 20) + bbase + (lane << 2);         \
        float4* lb_ = &xlds[wid][(n) & 1][0];                                  \
        gload_lds16(gp_ + 0,   (float*)(lb_ + 0));                             \
        gload_lds16(gp_ + 256, (float*)(lb_ + 64));                            \
        gload_lds16(gp_ + 512, (float*)(lb_ + 128));                           \
        gload_lds16(gp_ + 768, (float*)(lb_ + 192)); }

    // PINNED issue of phase Q's 16 uniform ds_read_b128 into xv (volatile).
#define DSREADV(xv, Qraw) {                                                    \
        int Q_ = (Qraw); if (Q_ > 511) Q_ = 511;                               \
        auto lp_ = (const __attribute__((address_space(3))) float4*)           \
                   &xlds[wid][(Q_ >> 4) & 1][(Q_ & 15) << 4];                  \
        _Pragma("unroll")                                                      \
        for (int q = 0; q < 16; ++q)                                           \
            asm volatile("ds_read_b128 %0, %1 offset:%2"                       \
                : "=v"(xv[q]) : "v"(lp_), "i"(q * 16) : "memory");             \
    }

#define WAIT_LGKM() { asm volatile("s_waitcnt lgkmcnt(0)" ::: "memory");       \
                      __builtin_amdgcn_sched_barrier(0); }

    // xpre[u] = scaled bias + dot(scaled w_ih, x_t), packed-fp32
#define PROJ(xpre, xv) {                                                       \
        _Pragma("unroll")                                                      \
        for (int u = 0; u < 4; ++u) {                                          \
            f2 A_ = pk_mul(wihp[0], f2lo(xv[4*u+0]));                          \
            f2 B_ = pk_mul(wihp[1], f2hi(xv[4*u+0]));                          \
            A_ = pk_fma(wihp[2], f2lo(xv[4*u+1]), A_);                         \
            B_ = pk_fma(wihp[3], f2hi(xv[4*u+1]), B_);                         \
            A_ = pk_fma(wihp[4], f2lo(xv[4*u+2]), A_);                         \
            B_ = pk_fma(wihp[5], f2hi(xv[4*u+2]), B_);                         \
            A_ = pk_fma(wihp[6], f2lo(xv[4*u+3]), A_);                         \
            B_ = pk_fma(wihp[7], f2hi(xv[4*u+3]), B_);                         \
            A_ = pk_add(A_, B_);                                               \
            xpre[u] = (bias + A_.x) + A_.y;                                    \
        } }

    // one recurrence step; dot + gather asm are NON-volatile (pure dataflow)
    // so LLVM can interleave PROJ/DSREAD/STORE into the chain's stall slots.
#define STEP(SU, xpv) {                                                        \
        float p0 = (xpv), p1, p2, p3;                                          \
        asm("s_nop 1\n\t"                                                      \
          "v_fmac_f32 %[q0], %[h], %[w0]\n\t"                                  \
          "v_mul_f32 %[q1], %[h], %[w1] row_ror:1 row_mask:0xf bank_mask:0xf\n\t" \
          "v_mul_f32 %[q2], %[h], %[w2] row_ror:2 row_mask:0xf bank_mask:0xf\n\t" \
          "v_mul_f32 %[q3], %[h], %[w3] row_ror:3 row_mask:0xf bank_mask:0xf\n\t" \
          "v_fmac_f32 %[q0], %[h], %[w4] row_ror:4 row_mask:0xf bank_mask:0xf\n\t" \
          "v_fmac_f32 %[q1], %[h], %[w5] row_ror:5 row_mask:0xf bank_mask:0xf\n\t" \
          "v_fmac_f32 %[q2], %[h], %[w6] row_ror:6 row_mask:0xf bank_mask:0xf\n\t" \
          "v_fmac_f32 %[q3], %[h], %[w7] row_ror:7 row_mask:0xf bank_mask:0xf\n\t" \
          "v_fmac_f32 %[q0], %[h], %[w8] row_ror:8 row_mask:0xf bank_mask:0xf\n\t" \
          "v_fmac_f32 %[q1], %[h], %[w9] row_ror:9 row_mask:0xf bank_mask:0xf\n\t" \
          "v_fmac_f32 %[q2], %[h], %[w10] row_ror:10 row_mask:0xf bank_mask:0xf\n\t" \
          "v_fmac_f32 %[q3], %[h], %[w11] row_ror:11 row_mask:0xf bank_mask:0xf\n\t" \
          "v_fmac_f32 %[q0], %[h], %[w12] row_ror:12 row_mask:0xf bank_mask:0xf\n\t" \
          "v_fmac_f32 %[q1], %[h], %[w13] row_ror:13 row_mask:0xf bank_mask:0xf\n\t" \
          "v_fmac_f32 %[q2], %[h], %[w14] row_ror:14 row_mask:0xf bank_mask:0xf\n\t" \
          "v_fmac_f32 %[q3], %[h], %[w15] row_ror:15 row_mask:0xf bank_mask:0xf"   \
          : [q0]"+v"(p0), [q1]"=&v"(p1), [q2]"=&v"(p2), [q3]"=&v"(p3)          \
          : [h]"v"(hv),                                                        \
            [w0]"v"(whh[0]),  [w1]"v"(whh[1]),  [w2]"v"(whh[2]),  [w3]"v"(whh[3]), \
            [w4]"v"(whh[4]),  [w5]"v"(whh[5]),  [w6]"v"(whh[6]),  [w7]"v"(whh[7]), \
            [w8]"v"(whh[8]),  [w9]"v"(whh[9]),  [w10]"v"(whh[10]),[w11]"v"(whh[11]),\
            [w12]"v"(whh[12]),[w13]"v"(whh[13]),[w14]"v"(whh[14]),[w15]"v"(whh[15]));\
        float arg = (p0 + p1) + (p2 + p3);                                     \
        float act = fmaf(mm, frcp(1.0f + fexp2(arg)), dd);                     \
        float qf, qg, qi, qo;                                                  \
        asm("v_mov_b32 %[A], %[x]\n\t"                                         \
          "v_mov_b32 %[B], %[x]\n\t"                                           \
          "s_nop 1\n\t"                                                        \
          "v_permlane16_swap_b32 %[A], %[B]\n\t"                               \
          "v_mov_b32 %[C], %[A]\n\t"                                           \
          "v_mov_b32 %[D], %[B]\n\t"                                           \
          "v_permlane32_swap_b32 %[A], %[C]\n\t"                               \
          "v_permlane32_swap_b32 %[B], %[D]"                                   \
          : [A]"=&v"(qf), [B]"=&v"(qi), [C]"=&v"(qg), [D]"=&v"(qo)             \
          : [x]"v"(act));                                                      \
        float ig = qi * qg;                                                    \
        float qo2 = qo + qo;                                                   \
        c = fmaf(c, qf, ig);                                                   \
        float rr = frcp(1.0f + fexp2(c));                                      \
        hv = fmaf(-qo2, rr, qo);                                               \
        sv = (SU) ? hv : sv;                                                   \
    }

#define STORE(pb) out[(pb) + lane] = sv;

    float4 xvA[16], xvB[16];
    float  xpre0[4], xpre1[4];

    // prologue
    GLOAD_CHUNK(0);
    GLOAD_CHUNK(1);
    asm volatile("s_waitcnt vmcnt(0)" ::: "memory");
    DSREADV(xvA, 0);
    WAIT_LGKM();
    PROJ(xpre0, xvA);
    DSREADV(xvB, 1);

#pragma unroll 1
    for (int P = 0; P < 512; P += 2) {
        DSREADV(xvA, P + 2);               // pinned early issue (phase P+2)
        {
            const int pb = PB(P);
            STEP(su0, xpre0[0]);
            STEP(su1, xpre0[1]);
            STEP(su2, xpre0[2]);
            STEP(su3, xpre0[3]);
            STORE(pb);
        }
        if ((P & 15) == 8)                 // chunk staging guaranteed done
            asm volatile("s_waitcnt vmcnt(0)" ::: "memory");
        WAIT_LGKM();                       // drains xvB (prev iter) + xvA (top)
        PROJ(xpre1, xvB);                  // phase P+1
        {
            const int pb = PB(P + 1);
            STEP(su0, xpre1[0]);
            STEP(su1, xpre1[1]);
            STEP(su2, xpre1[2]);
            STEP(su3, xpre1[3]);
            STORE(pb);
        }
        DSREADV(xvB, P + 3);               // pinned issue (phase P+3)
        PROJ(xpre0, xvA);                  // phase P+2 (already drained above)
        if ((P & 15) == 14 && P < 480)
            GLOAD_CHUNK((P >> 4) + 2);     // stage chunk+2, ~17 phases early
    }

#undef STEP
#undef STORE
#undef PROJ
#undef WAIT_LGKM
#undef DSREADV
#undef GLOAD_CHUNK
#undef PB
}

extern "C" void kernel_launch(void* const* d_in, const int* in_sizes, int n_in,
                              void* d_out, int out_size, void* d_ws, size_t ws_size,
                              hipStream_t stream)
{
    const float* images = (const float*)d_in[0];
    const float* w_ih   = (const float*)d_in[1];
    const float* w_hh   = (const float*)d_in[2];
    const float* b_ih   = (const float*)d_in[3];
    const float* b_hh   = (const float*)d_in[4];
    float* outp         = (float*)d_out;

    lstm_fused<<<dim3(256), dim3(256), 0, stream>>>(images, w_ih, w_hh, b_ih, b_hh, outp);
}